// Round 5
// baseline (195.657 us; speedup 1.0000x reference)
//
#include <hip/hip_runtime.h>
#include <math.h>

#define LRES 1024
#define TOPK 48
#define NEDGE (LRES*TOPK)

typedef short short8 __attribute__((ext_vector_type(8)));
typedef float f32x4  __attribute__((ext_vector_type(4)));

// ---- output layout (floats). Tuple concat: E, E_idx, E_s, E_idx_sub ----
#define OUT_E     0
#define OUT_EIDX  6291456          // 1024*48*128
#define OUT_ES    6340608          // + 49152
#define OUT_EIDX2 12632064         // + 6291456

// ---- workspace layout (float offsets) ----
#define WS_COORDS 0                // 1024*15 floats
#define WS_DNB    15360            // 49152 floats
#define WS_EIDX   64512            // 49152 ints
#define WS_WPE    113664           // 65536 shorts (32768 f): W_e B-frags, 16 ksteps (13 real + 3 zero)
#define WS_WPS    146432           // 163840 shorts (81920 f): W_s B-frags, 40 ksteps

// RBF recurrence constants.
// edgeE: mu = 2 + r*(4/3), invsig = 0.8  -> u=(d-2)*0.8, Delta = 16/15
#define DE 1.06666667f
#define QE 0.10273976f             // exp(-2*DE^2)
// edgeS: mu = 2 + r*(20/7), invsig = 0.4 -> u=(d-2)*0.4, Delta = 8/7
#define DS 1.14285714f
#define QS 0.07337053f             // exp(-2*DS^2)

// pair -> anchor index maps (N=0, Ca=1, C=2, O=3, Cb=4)
__constant__ int PA[24] = {0,2,3,4,1,1,1,1,0,0,0,4,4,3,0,2,3,4,2,3,4,2,3,2};
__constant__ int PB[24] = {0,2,3,4,0,2,3,4,2,3,4,2,3,2,1,1,1,1,0,0,0,4,4,3};

__device__ inline short f2bf(float f) {           // RNE, off hot path (weights)
    unsigned u = __float_as_uint(f);
    unsigned r = (u + 0x7FFFu + ((u >> 16) & 1u)) >> 16;
    return (short)r;
}

// pack 8 floats -> short8 bf16 by truncation: 1 v_perm per 2 values
__device__ inline short8 pack8(const float* fv) {
    union { short8 s; unsigned u[4]; } r;
    #pragma unroll
    for (int i = 0; i < 4; ++i)
        r.u[i] = __builtin_amdgcn_perm(__float_as_uint(fv[2*i+1]),
                                       __float_as_uint(fv[2*i]), 0x07060302u);
    return r.s;
}

// ============ K_PRE: topk (blocks 0..255) | pack (256..895) | coords (896..899) =====
__global__ __launch_bounds__(256) void k_pre(const float* __restrict__ X,
                                             const float* __restrict__ mask,
                                             const float* __restrict__ We,
                                             const float* __restrict__ Ws,
                                             float* __restrict__ coords,
                                             short* __restrict__ WpE,
                                             short* __restrict__ WpS,
                                             float* __restrict__ Dnb,
                                             int* __restrict__ Eidx,
                                             float* __restrict__ out) {
    int blk = blockIdx.x, t = threadIdx.x;
    if (blk < 256) {
        // ---------------- top-48 per row, one wave per row ----------------
        __shared__ float sCa[LRES*3];
        __shared__ float sM[LRES];
        for (int j = t; j < LRES; j += 256) {
            sCa[j*3+0] = X[j*111 + 3];
            sCa[j*3+1] = X[j*111 + 4];
            sCa[j*3+2] = X[j*111 + 5];
            sM[j] = mask[j];
        }
        __syncthreads();
        int w = t >> 6, lane = t & 63;
        int i = blk * 4 + w;
        float cx = sCa[i*3], cy = sCa[i*3+1], cz = sCa[i*3+2];
        float mi = sM[i];
        float dv[16], m2v[16];
        float lmax = -1e30f;
        #pragma unroll
        for (int s = 0; s < 16; ++s) {
            int j = s*64 + lane;
            float dx = cx - sCa[j*3], dy = cy - sCa[j*3+1], dz = cz - sCa[j*3+2];
            float d  = __builtin_amdgcn_sqrtf(dx*dx + dy*dy + dz*dz + 1e-6f);
            float m2 = mi * sM[j];
            dv[s] = m2 * d; m2v[s] = m2;
            lmax = fmaxf(lmax, dv[s]);
        }
        #pragma unroll
        for (int off = 32; off; off >>= 1) lmax = fmaxf(lmax, __shfl_xor(lmax, off));
        // keys: positive-float bits << 10 | index (unique, tie -> lowest index)
        unsigned long long key[16];
        #pragma unroll
        for (int s = 0; s < 16; ++s) {
            float dadj = dv[s] + (1.0f - m2v[s]) * lmax;
            key[s] = (((unsigned long long)__float_as_uint(dadj)) << 10) | (unsigned)(s*64 + lane);
        }
        unsigned long long mkey = key[0];
        #pragma unroll
        for (int s = 1; s < 16; ++s) mkey = (key[s] < mkey) ? key[s] : mkey;
        for (int it = 0; it < TOPK; ++it) {
            unsigned long long wk = mkey;
            #pragma unroll
            for (int off = 32; off; off >>= 1) {
                unsigned long long o = __shfl_xor(wk, off);
                wk = (o < wk) ? o : wk;
            }
            if (lane == 0) {
                int j = (int)(wk & 1023u);
                int id = i*TOPK + it;
                Dnb[id]  = __uint_as_float((unsigned)(wk >> 10));
                Eidx[id] = j;
                out[OUT_EIDX  + id] = (float)j;
                out[OUT_EIDX2 + id] = (float)j;
            }
            if (mkey == wk) {   // winning lane: constant-index clear + rescan (stays in VGPRs)
                #pragma unroll
                for (int s = 0; s < 16; ++s)
                    key[s] = (key[s] == wk) ? ~0ull : key[s];
                mkey = key[0];
                #pragma unroll
                for (int s = 1; s < 16; ++s) mkey = (key[s] < mkey) ? key[s] : mkey;
            }
        }
    } else if (blk < 896) {
        // ---------------- pack W_e / W_s into MFMA B-fragment order ----------------
        int g = (blk - 256) * 256 + t;
        if (g < 8*16*64*8) {          // WpE: 16 ksteps, 13 real + 3 zero-pad
            int j = g & 7, lane = (g >> 3) & 63, gg = g >> 9;
            int ks = gg & 15, nt = gg >> 4;
            int n = nt*16 + (lane & 15), k = ks*32 + (lane >> 4)*8 + j;
            WpE[g] = (k < 416) ? f2bf(We[n*416 + k]) : (short)0;
        }
        if (g < 8*40*64*8) {          // WpS: 40 ksteps
            int j = g & 7, lane = (g >> 3) & 63, gg = g >> 9;
            int ks = gg % 40, nt = gg / 40;
            int n = nt*16 + (lane & 15), k = ks*32 + (lane >> 4)*8 + j;
            WpS[g] = f2bf(Ws[n*1280 + k]);
        }
    } else {
        // ---------------- per-residue coords N,Ca,C,O,Cb ----------------
        int r = (blk - 896) * 256 + t;
        if (r >= LRES) return;
        const float* xr = X + r * 111;
        float N[3], Ca[3], C[3], O[3], bv[3], cv[3], av[3];
        #pragma unroll
        for (int d = 0; d < 3; ++d) {
            N[d]  = xr[0*3 + d];  Ca[d] = xr[1*3 + d];
            C[d]  = xr[2*3 + d];  O[d]  = xr[4*3 + d];
            bv[d] = Ca[d] - N[d]; cv[d] = C[d] - Ca[d];
        }
        av[0] = bv[1]*cv[2] - bv[2]*cv[1];
        av[1] = bv[2]*cv[0] - bv[0]*cv[2];
        av[2] = bv[0]*cv[1] - bv[1]*cv[0];
        float* o = coords + r * 15;
        #pragma unroll
        for (int d = 0; d < 3; ++d) {
            float Cb = -0.58273431f*av[d] + 0.56802827f*bv[d] - 0.54067466f*cv[d] + Ca[d];
            o[0*3+d] = N[d]; o[1*3+d] = Ca[d]; o[2*3+d] = C[d];
            o[3*3+d] = O[d]; o[4*3+d] = Cb;
        }
    }
}

// ============ K_EDGE: edgeS (even blocks) | edgeE (odd blocks), interleaved ============
// Both: 32 edges/block, 4 waves, K-split across waves, 8 N-tiles each,
// B-fragments software-pipelined (prefetch next kstep before feature compute).
__global__ __launch_bounds__(256, 3) void k_edge(const float* __restrict__ coords,
                                                 const float* __restrict__ X,
                                                 const float* __restrict__ amask,
                                                 const short* __restrict__ WpE,
                                                 const short* __restrict__ WpS,
                                                 const float* __restrict__ Dnb,
                                                 const int* __restrict__ Eidx,
                                                 const int* __restrict__ ri,
                                                 const int* __restrict__ ch,
                                                 const float* __restrict__ Wpos,
                                                 const float* __restrict__ bpos,
                                                 const float* __restrict__ ge,
                                                 const float* __restrict__ be,
                                                 const float* __restrict__ gs,
                                                 const float* __restrict__ bs,
                                                 float* __restrict__ out) {
    __shared__ float smem[5808];
    int t = threadIdx.x;
    int w = t >> 6, lane = t & 63, quad = lane >> 4, l16 = lane & 15;
    int id0 = (blockIdx.x >> 1) * 32;

    if ((blockIdx.x & 1) == 0) {
        // =============== edgeS: 1280 -> 128 matvec + LN ===============
        float* u_hbuf = smem;                 // 32*132 = 4224
        float* sA3    = smem + 4224;          // 45
        float* part   = smem + 4272;          // 256
        float* part2  = smem + 4528;          // 256
        float* smu    = smem + 4784;          // 32
        float* srs    = smem + 4816;          // 32
        int i0 = id0 / TOPK;

        if (t < 45) {
            int rr = i0 + t / 15;
            if (rr > LRES-1) rr = LRES-1;
            sA3[t] = coords[rr*15 + t%15];
        }
        int s1 = 4*w + quad;                  // sidechain atom for half 0
        float S[2][2][3], am[2][2];
        int bA[2];
        #pragma unroll
        for (int mt = 0; mt < 2; ++mt) {
            int id = id0 + mt*16 + l16;
            int j  = Eidx[id];
            bA[mt] = (id / TOPK - i0) * 15;
            const float* xp = X + (j*37 + 5)*3;
            const float* ap = amask + j*37 + 5;
            #pragma unroll
            for (int h = 0; h < 2; ++h) {
                int s = s1 + h*16;
                S[mt][h][0] = xp[s*3+0];
                S[mt][h][1] = xp[s*3+1];
                S[mt][h][2] = xp[s*3+2];
                am[mt][h]   = ap[s];
            }
        }
        __syncthreads();

        f32x4 acc[2][8] = {};
        const short8* bp = (const short8*)WpS;
        short8 bnext[8];
        #pragma unroll
        for (int nt = 0; nt < 8; ++nt) bnext[nt] = bp[(nt*40 + w)*64 + lane];

        #pragma unroll
        for (int st = 0; st < 10; ++st) {     // ks = w + 4*st; a = st>>1, h = st&1
            int a = st >> 1, h = st & 1;
            short8 bcur[8];
            #pragma unroll
            for (int nt = 0; nt < 8; ++nt) bcur[nt] = bnext[nt];
            if (st < 9) {
                int ksn = w + (st + 1)*4;
                #pragma unroll
                for (int nt = 0; nt < 8; ++nt) bnext[nt] = bp[(nt*40 + ksn)*64 + lane];
            }
            short8 afrag[2];
            #pragma unroll
            for (int mt = 0; mt < 2; ++mt) {
                float dx = sA3[bA[mt] + a*3+0] - S[mt][h][0];
                float dy = sA3[bA[mt] + a*3+1] - S[mt][h][1];
                float dz = sA3[bA[mt] + a*3+2] - S[mt][h][2];
                float d  = __builtin_amdgcn_sqrtf(fmaf(dz,dz,fmaf(dy,dy,fmaf(dx,dx,1e-6f))));
                float u  = fmaf(d, 0.4f, -0.8f);
                float e0 = __expf(-u*u) * am[mt][h];
                float g  = __expf(fmaf(2.0f*DS, u, -(DS*DS)));
                float fv[8];
                fv[0] = e0;
                #pragma unroll
                for (int r = 1; r < 8; ++r) { e0 *= g; g *= QS; fv[r] = e0; }
                afrag[mt] = pack8(fv);
            }
            #pragma unroll
            for (int nt = 0; nt < 8; ++nt) {
                acc[0][nt] = __builtin_amdgcn_mfma_f32_16x16x32_bf16(afrag[0], bcur[nt], acc[0][nt], 0,0,0);
                acc[1][nt] = __builtin_amdgcn_mfma_f32_16x16x32_bf16(afrag[1], bcur[nt], acc[1][nt], 0,0,0);
            }
        }

        float* hbuf = u_hbuf;
        __syncthreads();
        for (int ww = 0; ww < 4; ++ww) {
            if (w == ww) {
                #pragma unroll
                for (int mt = 0; mt < 2; ++mt)
                #pragma unroll
                for (int nt = 0; nt < 8; ++nt)
                #pragma unroll
                for (int r = 0; r < 4; ++r) {
                    int e = mt*16 + quad*4 + r;
                    float* p = &hbuf[e*132 + nt*16 + l16];
                    if (ww == 0) *p = acc[mt][nt][r]; else *p += acc[mt][nt][r];
                }
            }
            __syncthreads();
        }
        {
            int e = t >> 3, p = t & 7;
            float s = 0.f, s2 = 0.f;
            #pragma unroll
            for (int q = 0; q < 16; ++q) {
                float x = hbuf[e*132 + p*16 + q];
                s += x; s2 += x*x;
            }
            part[e*8+p] = s; part2[e*8+p] = s2;
        }
        __syncthreads();
        if (t < 32) {
            float s = 0.f, s2 = 0.f;
            #pragma unroll
            for (int p = 0; p < 8; ++p) { s += part[t*8+p]; s2 += part2[t*8+p]; }
            float mu = s * (1.0f/128.0f);
            float var = s2 * (1.0f/128.0f) - mu*mu;
            smu[t] = mu; srs[t] = rsqrtf(var + 1e-5f);
        }
        __syncthreads();
        for (int it = t; it < 32*32; it += 256) {
            int e = it >> 5, f = (it & 31)*4;
            float4 x = *(const float4*)&hbuf[e*132 + f];
            float4 G = *(const float4*)&gs[f];
            float4 B = *(const float4*)&bs[f];
            float mu = smu[e], rs = srs[e];
            float4 r;
            r.x = G.x*(x.x - mu)*rs + B.x;
            r.y = G.y*(x.y - mu)*rs + B.y;
            r.z = G.z*(x.z - mu)*rs + B.z;
            r.w = G.w*(x.w - mu)*rs + B.w;
            *(float4*)&out[OUT_ES + (size_t)(id0 + e)*128 + f] = r;
        }
    } else {
        // =============== edgeE: 416 -> 128 matvec + LN ===============
        float* sA     = smem;                 // 480
        float* sB     = smem + 480;           // 480
        float* u_hbuf = smem + 960;           // 4224 (sdist 32*27 + sposf 32*17 inside)
        float* part   = smem + 5184;          // 256
        float* part2  = smem + 5440;          // 256
        float* smu    = smem + 5696;          // 32
        float* srs    = smem + 5728;          // 32
        int*   sdpos  = (int*)(smem + 5760);  // 32
        float* sdist  = u_hbuf;               // stride 27
        float* sposf  = u_hbuf + 32*27;       // stride 17

        if (t < 32) {
            int id = id0 + t, i = id / TOPK, j = Eidx[id];
            int off = ri[i] - ri[j];
            sdpos[t] = (ch[i] == ch[j]) ? min(max(off + 32, 0), 64) : 65;
            sdist[t*27] = Dnb[id];
        }
        for (int it = t; it < 32*15; it += 256) {
            int e = it / 15, q = it % 15;
            int id = id0 + e, i = id / TOPK, j = Eidx[id];
            sA[e*15+q] = coords[i*15+q];
            sB[e*15+q] = coords[j*15+q];
        }
        __syncthreads();
        for (int it = t; it < 32*24; it += 256) {
            int e = it / 24, p = it % 24, a = PA[p], b = PB[p];
            float dx = sA[e*15+a*3+0] - sB[e*15+b*3+0];
            float dy = sA[e*15+a*3+1] - sB[e*15+b*3+1];
            float dz = sA[e*15+a*3+2] - sB[e*15+b*3+2];
            sdist[e*27 + 1 + p] = __builtin_amdgcn_sqrtf(dx*dx + dy*dy + dz*dz + 1e-6f);
        }
        for (int it = t; it < 32*16; it += 256) {
            int e = it >> 4, c = it & 15;
            sposf[e*17 + c] = Wpos[c*66 + sdpos[e]] + bpos[c];
        }
        __syncthreads();

        f32x4 acc[2][8] = {};
        const short8* bp = (const short8*)WpE;
        float rb = (quad & 1) ? 8.0f*DE : 0.0f;
        short8 bnext[8];
        #pragma unroll
        for (int nt = 0; nt < 8; ++nt) bnext[nt] = bp[(nt*16 + w)*64 + lane];

        #pragma unroll
        for (int st = 0; st < 4; ++st) {      // ks = w + 4*st; ks 13..15 have zero B
            int ks = w + st*4;
            short8 bcur[8];
            #pragma unroll
            for (int nt = 0; nt < 8; ++nt) bcur[nt] = bnext[nt];
            if (st < 3) {
                int ksn = ks + 4;
                #pragma unroll
                for (int nt = 0; nt < 8; ++nt) bnext[nt] = bp[(nt*16 + ksn)*64 + lane];
            }
            short8 afrag[2];
            #pragma unroll
            for (int mt = 0; mt < 2; ++mt) {
                int e = mt*16 + l16;
                float fv[8];
                if (ks == 0 && quad < 2) {
                    #pragma unroll
                    for (int j = 0; j < 8; ++j) fv[j] = sposf[e*17 + quad*8 + j];
                } else {
                    int p = (ks == 0) ? 0 : (2*ks - 1 + (quad >> 1));
                    float d = sdist[e*27 + p];    // garbage-but-finite for ks>12 (B=0)
                    float u = fmaf(d, 0.8f, -1.6f) - rb;
                    float e0 = __expf(-u*u);
                    float g  = __expf(fmaf(2.0f*DE, u, -(DE*DE)));
                    fv[0] = e0;
                    #pragma unroll
                    for (int r = 1; r < 8; ++r) { e0 *= g; g *= QE; fv[r] = e0; }
                }
                afrag[mt] = pack8(fv);
            }
            #pragma unroll
            for (int nt = 0; nt < 8; ++nt) {
                acc[0][nt] = __builtin_amdgcn_mfma_f32_16x16x32_bf16(afrag[0], bcur[nt], acc[0][nt], 0,0,0);
                acc[1][nt] = __builtin_amdgcn_mfma_f32_16x16x32_bf16(afrag[1], bcur[nt], acc[1][nt], 0,0,0);
            }
        }

        float* hbuf = u_hbuf;
        __syncthreads();
        for (int ww = 0; ww < 4; ++ww) {
            if (w == ww) {
                #pragma unroll
                for (int mt = 0; mt < 2; ++mt)
                #pragma unroll
                for (int nt = 0; nt < 8; ++nt)
                #pragma unroll
                for (int r = 0; r < 4; ++r) {
                    int e = mt*16 + quad*4 + r;
                    float* p = &hbuf[e*132 + nt*16 + l16];
                    if (ww == 0) *p = acc[mt][nt][r]; else *p += acc[mt][nt][r];
                }
            }
            __syncthreads();
        }
        {
            int e = t >> 3, p = t & 7;
            float s = 0.f, s2 = 0.f;
            #pragma unroll
            for (int q = 0; q < 16; ++q) {
                float x = hbuf[e*132 + p*16 + q];
                s += x; s2 += x*x;
            }
            part[e*8+p] = s; part2[e*8+p] = s2;
        }
        __syncthreads();
        if (t < 32) {
            float s = 0.f, s2 = 0.f;
            #pragma unroll
            for (int p = 0; p < 8; ++p) { s += part[t*8+p]; s2 += part2[t*8+p]; }
            float mu = s * (1.0f/128.0f);
            float var = s2 * (1.0f/128.0f) - mu*mu;
            smu[t] = mu; srs[t] = rsqrtf(var + 1e-5f);
        }
        __syncthreads();
        for (int it = t; it < 32*32; it += 256) {
            int e = it >> 5, f = (it & 31)*4;
            float4 x = *(const float4*)&hbuf[e*132 + f];
            float4 G = *(const float4*)&ge[f];
            float4 B = *(const float4*)&be[f];
            float mu = smu[e], rs = srs[e];
            float4 r;
            r.x = G.x*(x.x - mu)*rs + B.x;
            r.y = G.y*(x.y - mu)*rs + B.y;
            r.z = G.z*(x.z - mu)*rs + B.z;
            r.w = G.w*(x.w - mu)*rs + B.w;
            *(float4*)&out[OUT_E + (size_t)(id0 + e)*128 + f] = r;
        }
    }
}

extern "C" void kernel_launch(void* const* d_in, const int* in_sizes, int n_in,
                              void* d_out, int out_size, void* d_ws, size_t ws_size,
                              hipStream_t stream) {
    (void)in_sizes; (void)n_in; (void)out_size; (void)ws_size;
    const float* X     = (const float*)d_in[0];
    const float* mask  = (const float*)d_in[2];
    const float* amask = (const float*)d_in[3];
    const int*   ri    = (const int*)d_in[4];
    const int*   ch    = (const int*)d_in[6];
    const float* Wpos  = (const float*)d_in[7];
    const float* bpos  = (const float*)d_in[8];
    const float* We    = (const float*)d_in[9];
    const float* ge    = (const float*)d_in[10];
    const float* be    = (const float*)d_in[11];
    const float* Ws    = (const float*)d_in[12];
    const float* gs    = (const float*)d_in[13];
    const float* bs    = (const float*)d_in[14];

    float* out    = (float*)d_out;
    float* ws     = (float*)d_ws;
    float* coords = ws + WS_COORDS;
    float* Dnb    = ws + WS_DNB;
    int*   Eidx   = (int*)(ws + WS_EIDX);
    short* WpE    = (short*)(ws + WS_WPE);
    short* WpS    = (short*)(ws + WS_WPS);

    k_pre <<<dim3(900),  dim3(256), 0, stream>>>(X, mask, We, Ws, coords,
                                                 WpE, WpS, Dnb, Eidx, out);
    k_edge<<<dim3(3072), dim3(256), 0, stream>>>(coords, X, amask, WpE, WpS,
                                                 Dnb, Eidx, ri, ch, Wpos, bpos,
                                                 ge, be, gs, bs, out);
}

// Round 6
// 190.846 us; speedup vs baseline: 1.0252x; 1.0252x over previous
//
#include <hip/hip_runtime.h>
#include <math.h>

#define LRES 1024
#define TOPK 48
#define NEDGE (LRES*TOPK)

typedef short short8 __attribute__((ext_vector_type(8)));
typedef float f32x4  __attribute__((ext_vector_type(4)));

// ---- output layout (floats). Tuple concat: E, E_idx, E_s, E_idx_sub ----
#define OUT_E     0
#define OUT_EIDX  6291456          // 1024*48*128
#define OUT_ES    6340608          // + 49152
#define OUT_EIDX2 12632064         // + 6291456

// ---- workspace layout (float offsets) ----
#define WS_COORDS 0                // 1024*15 floats
#define WS_DNB    15360            // 49152 floats
#define WS_EIDX   64512            // 49152 ints
#define WS_WPE    113664           // 65536 shorts: W_e B-frags, 16 ksteps (13 real + 3 zero)
#define WS_WPS    146432           // 163840 shorts: W_s B-frags, 40 ksteps

// RBF recurrence constants.
#define DE 1.06666667f
#define QE 0.10273976f             // exp(-2*DE^2)
#define DS 1.14285714f
#define QS 0.07337053f             // exp(-2*DS^2)

// pair -> anchor index maps (N=0, Ca=1, C=2, O=3, Cb=4)
__constant__ int PA[24] = {0,2,3,4,1,1,1,1,0,0,0,4,4,3,0,2,3,4,2,3,4,2,3,2};
__constant__ int PB[24] = {0,2,3,4,0,2,3,4,2,3,4,2,3,2,1,1,1,1,0,0,0,4,4,3};

__device__ inline short f2bf(float f) {           // RNE, off hot path (weights)
    unsigned u = __float_as_uint(f);
    unsigned r = (u + 0x7FFFu + ((u >> 16) & 1u)) >> 16;
    return (short)r;
}

// pack 8 floats -> short8 bf16 by truncation: 1 v_perm per 2 values
__device__ inline short8 pack8(const float* fv) {
    union { short8 s; unsigned u[4]; } r;
    #pragma unroll
    for (int i = 0; i < 4; ++i)
        r.u[i] = __builtin_amdgcn_perm(__float_as_uint(fv[2*i+1]),
                                       __float_as_uint(fv[2*i]), 0x07060302u);
    return r.s;
}

// ============ K_PRE: topk (blocks 0..255) | pack (256..895) | coords (896..899) =====
__global__ __launch_bounds__(256) void k_pre(const float* __restrict__ X,
                                             const float* __restrict__ mask,
                                             const float* __restrict__ We,
                                             const float* __restrict__ Ws,
                                             float* __restrict__ coords,
                                             short* __restrict__ WpE,
                                             short* __restrict__ WpS,
                                             float* __restrict__ Dnb,
                                             int* __restrict__ Eidx,
                                             float* __restrict__ out) {
    int blk = blockIdx.x, t = threadIdx.x;
    if (blk < 256) {
        __shared__ float sCa[LRES*3];
        __shared__ float sM[LRES];
        for (int j = t; j < LRES; j += 256) {
            sCa[j*3+0] = X[j*111 + 3];
            sCa[j*3+1] = X[j*111 + 4];
            sCa[j*3+2] = X[j*111 + 5];
            sM[j] = mask[j];
        }
        __syncthreads();
        int w = t >> 6, lane = t & 63;
        int i = blk * 4 + w;
        float cx = sCa[i*3], cy = sCa[i*3+1], cz = sCa[i*3+2];
        float mi = sM[i];
        float dv[16], m2v[16];
        float lmax = -1e30f;
        #pragma unroll
        for (int s = 0; s < 16; ++s) {
            int j = s*64 + lane;
            float dx = cx - sCa[j*3], dy = cy - sCa[j*3+1], dz = cz - sCa[j*3+2];
            float d  = __builtin_amdgcn_sqrtf(dx*dx + dy*dy + dz*dz + 1e-6f);
            float m2 = mi * sM[j];
            dv[s] = m2 * d; m2v[s] = m2;
            lmax = fmaxf(lmax, dv[s]);
        }
        #pragma unroll
        for (int off = 32; off; off >>= 1) lmax = fmaxf(lmax, __shfl_xor(lmax, off));
        unsigned long long key[16];
        #pragma unroll
        for (int s = 0; s < 16; ++s) {
            float dadj = dv[s] + (1.0f - m2v[s]) * lmax;
            key[s] = (((unsigned long long)__float_as_uint(dadj)) << 10) | (unsigned)(s*64 + lane);
        }
        unsigned long long mkey = key[0];
        #pragma unroll
        for (int s = 1; s < 16; ++s) mkey = (key[s] < mkey) ? key[s] : mkey;
        for (int it = 0; it < TOPK; ++it) {
            unsigned long long wk = mkey;
            #pragma unroll
            for (int off = 32; off; off >>= 1) {
                unsigned long long o = __shfl_xor(wk, off);
                wk = (o < wk) ? o : wk;
            }
            if (lane == 0) {
                int j = (int)(wk & 1023u);
                int id = i*TOPK + it;
                Dnb[id]  = __uint_as_float((unsigned)(wk >> 10));
                Eidx[id] = j;
                out[OUT_EIDX  + id] = (float)j;
                out[OUT_EIDX2 + id] = (float)j;
            }
            if (mkey == wk) {
                #pragma unroll
                for (int s = 0; s < 16; ++s)
                    key[s] = (key[s] == wk) ? ~0ull : key[s];
                mkey = key[0];
                #pragma unroll
                for (int s = 1; s < 16; ++s) mkey = (key[s] < mkey) ? key[s] : mkey;
            }
        }
    } else if (blk < 896) {
        int g = (blk - 256) * 256 + t;
        if (g < 8*16*64*8) {          // WpE: 16 ksteps, 13 real + 3 zero-pad
            int j = g & 7, lane = (g >> 3) & 63, gg = g >> 9;
            int ks = gg & 15, nt = gg >> 4;
            int n = nt*16 + (lane & 15), k = ks*32 + (lane >> 4)*8 + j;
            WpE[g] = (k < 416) ? f2bf(We[n*416 + k]) : (short)0;
        }
        if (g < 8*40*64*8) {          // WpS: 40 ksteps
            int j = g & 7, lane = (g >> 3) & 63, gg = g >> 9;
            int ks = gg % 40, nt = gg / 40;
            int n = nt*16 + (lane & 15), k = ks*32 + (lane >> 4)*8 + j;
            WpS[g] = f2bf(Ws[n*1280 + k]);
        }
    } else {
        int r = (blk - 896) * 256 + t;
        if (r >= LRES) return;
        const float* xr = X + r * 111;
        float N[3], Ca[3], C[3], O[3], bv[3], cv[3], av[3];
        #pragma unroll
        for (int d = 0; d < 3; ++d) {
            N[d]  = xr[0*3 + d];  Ca[d] = xr[1*3 + d];
            C[d]  = xr[2*3 + d];  O[d]  = xr[4*3 + d];
            bv[d] = Ca[d] - N[d]; cv[d] = C[d] - Ca[d];
        }
        av[0] = bv[1]*cv[2] - bv[2]*cv[1];
        av[1] = bv[2]*cv[0] - bv[0]*cv[2];
        av[2] = bv[0]*cv[1] - bv[1]*cv[0];
        float* o = coords + r * 15;
        #pragma unroll
        for (int d = 0; d < 3; ++d) {
            float Cb = -0.58273431f*av[d] + 0.56802827f*bv[d] - 0.54067466f*cv[d] + Ca[d];
            o[0*3+d] = N[d]; o[1*3+d] = Ca[d]; o[2*3+d] = C[d];
            o[3*3+d] = O[d]; o[4*3+d] = Cb;
        }
    }
}

// ============ K_EDGE: edgeS (blocks 0..1535) | edgeE (1536..3071) ============
// 32 edges/block, 4 waves, K-split across waves, 8 N-tiles each.
// Epilogue: parallel tree reduce — w0/w1 write A/B, w2/w3 add, all combine+LN.
// LDS: A(4224) B(4224) part(256) part2(256) smu(32) srs(32) sdpos(32) sA3(48)
__global__ __launch_bounds__(256, 3) void k_edge(const float* __restrict__ coords,
                                                 const float* __restrict__ X,
                                                 const float* __restrict__ amask,
                                                 const short* __restrict__ WpE,
                                                 const short* __restrict__ WpS,
                                                 const float* __restrict__ Dnb,
                                                 const int* __restrict__ Eidx,
                                                 const int* __restrict__ ri,
                                                 const int* __restrict__ ch,
                                                 const float* __restrict__ Wpos,
                                                 const float* __restrict__ bpos,
                                                 const float* __restrict__ ge,
                                                 const float* __restrict__ be,
                                                 const float* __restrict__ gs,
                                                 const float* __restrict__ bs,
                                                 float* __restrict__ out) {
    __shared__ float smem[9104];
    float* Ar    = smem;            // 4224 (stride-132 rows; edgeE setup aliases here)
    float* Br    = smem + 4224;     // 4224 (edgeE sA/sB alias here)
    float* part  = smem + 8448;     // 256
    float* part2 = smem + 8704;     // 256
    float* smu   = smem + 8960;     // 32
    float* srs   = smem + 8992;     // 32
    int*   sdpos = (int*)(smem + 9024); // 32
    float* sA3   = smem + 9056;     // 48

    int t = threadIdx.x;
    int w = t >> 6, lane = t & 63, quad = lane >> 4, l16 = lane & 15;
    bool isS = blockIdx.x < 1536;
    int id0 = (isS ? blockIdx.x : blockIdx.x - 1536) * 32;

    f32x4 acc[2][8] = {};
    size_t outBase;
    const float *gW, *bW;

    if (isS) {
        // =============== edgeS: 1280 -> 128 matvec ===============
        outBase = OUT_ES; gW = gs; bW = bs;
        int i0 = id0 / TOPK;
        if (t < 45) {
            int rr = i0 + t / 15;
            if (rr > LRES-1) rr = LRES-1;
            sA3[t] = coords[rr*15 + t%15];
        }
        int s1 = 4*w + quad;
        float S[2][2][3], am[2][2];
        int bA[2];
        #pragma unroll
        for (int mt = 0; mt < 2; ++mt) {
            int id = id0 + mt*16 + l16;
            int j  = Eidx[id];
            bA[mt] = (id / TOPK - i0) * 15;
            const float* xp = X + (j*37 + 5)*3;
            const float* ap = amask + j*37 + 5;
            #pragma unroll
            for (int h = 0; h < 2; ++h) {
                int s = s1 + h*16;
                S[mt][h][0] = xp[s*3+0];
                S[mt][h][1] = xp[s*3+1];
                S[mt][h][2] = xp[s*3+2];
                am[mt][h]   = ap[s];
            }
        }
        __syncthreads();

        const short8* bp = (const short8*)WpS;
        for (int a = 0; a < 5; ++a) {
            float A[2][3];
            #pragma unroll
            for (int mt = 0; mt < 2; ++mt) {
                A[mt][0] = sA3[bA[mt] + a*3+0];
                A[mt][1] = sA3[bA[mt] + a*3+1];
                A[mt][2] = sA3[bA[mt] + a*3+2];
            }
            #pragma unroll
            for (int h = 0; h < 2; ++h) {
                int ks = a*8 + w + h*4;
                short8 afrag[2];
                #pragma unroll
                for (int mt = 0; mt < 2; ++mt) {
                    float dx = A[mt][0] - S[mt][h][0];
                    float dy = A[mt][1] - S[mt][h][1];
                    float dz = A[mt][2] - S[mt][h][2];
                    float d  = __builtin_amdgcn_sqrtf(fmaf(dz,dz,fmaf(dy,dy,fmaf(dx,dx,1e-6f))));
                    float u  = fmaf(d, 0.4f, -0.8f);
                    float e0 = __expf(-u*u) * am[mt][h];
                    float g  = __expf(fmaf(2.0f*DS, u, -(DS*DS)));
                    float fv[8];
                    fv[0] = e0;
                    #pragma unroll
                    for (int r = 1; r < 8; ++r) { e0 *= g; g *= QS; fv[r] = e0; }
                    afrag[mt] = pack8(fv);
                }
                #pragma unroll
                for (int nt = 0; nt < 8; ++nt) {
                    short8 b = bp[(nt*40 + ks)*64 + lane];
                    acc[0][nt] = __builtin_amdgcn_mfma_f32_16x16x32_bf16(afrag[0], b, acc[0][nt], 0,0,0);
                    acc[1][nt] = __builtin_amdgcn_mfma_f32_16x16x32_bf16(afrag[1], b, acc[1][nt], 0,0,0);
                }
            }
        }
        // no barrier needed: K-loop reads only sA3/registers; A/B untouched
    } else {
        // =============== edgeE: 416 -> 128 matvec ===============
        outBase = OUT_E; gW = ge; bW = be;
        float* sdist = Ar;              // stride 27  (864 + OOB-pad reads, all < 4224)
        float* sposf = Ar + 900;        // stride 17  (544)
        float* sA    = Br;              // 480
        float* sB    = Br + 480;        // 480

        if (t < 32) {
            int id = id0 + t, i = id / TOPK, j = Eidx[id];
            int off = ri[i] - ri[j];
            sdpos[t] = (ch[i] == ch[j]) ? min(max(off + 32, 0), 64) : 65;
            sdist[t*27] = Dnb[id];
        }
        for (int it = t; it < 32*15; it += 256) {
            int e = it / 15, q = it % 15;
            int id = id0 + e, i = id / TOPK, j = Eidx[id];
            sA[e*15+q] = coords[i*15+q];
            sB[e*15+q] = coords[j*15+q];
        }
        __syncthreads();
        for (int it = t; it < 32*24; it += 256) {
            int e = it / 24, p = it % 24, a = PA[p], b = PB[p];
            float dx = sA[e*15+a*3+0] - sB[e*15+b*3+0];
            float dy = sA[e*15+a*3+1] - sB[e*15+b*3+1];
            float dz = sA[e*15+a*3+2] - sB[e*15+b*3+2];
            sdist[e*27 + 1 + p] = __builtin_amdgcn_sqrtf(dx*dx + dy*dy + dz*dz + 1e-6f);
        }
        for (int it = t; it < 32*16; it += 256) {
            int e = it >> 4, c = it & 15;
            sposf[e*17 + c] = Wpos[c*66 + sdpos[e]] + bpos[c];
        }
        __syncthreads();

        const short8* bp = (const short8*)WpE;
        float rb = (quad & 1) ? 8.0f*DE : 0.0f;
        for (int ks = w; ks < 16; ks += 4) {     // ks 13..15: zero B (padded)
            short8 afrag[2];
            #pragma unroll
            for (int mt = 0; mt < 2; ++mt) {
                int e = mt*16 + l16;
                float fv[8];
                if (ks == 0 && quad < 2) {
                    #pragma unroll
                    for (int j = 0; j < 8; ++j) fv[j] = sposf[e*17 + quad*8 + j];
                } else {
                    int p = (ks == 0) ? 0 : (2*ks - 1 + (quad >> 1));
                    float d = sdist[e*27 + p];   // ks>12: garbage-but-finite, B=0
                    float u = fmaf(d, 0.8f, -1.6f) - rb;
                    float e0 = __expf(-u*u);
                    float g  = __expf(fmaf(2.0f*DE, u, -(DE*DE)));
                    fv[0] = e0;
                    #pragma unroll
                    for (int r = 1; r < 8; ++r) { e0 *= g; g *= QE; fv[r] = e0; }
                }
                afrag[mt] = pack8(fv);
            }
            #pragma unroll
            for (int nt = 0; nt < 8; ++nt) {
                short8 b = bp[(nt*16 + ks)*64 + lane];
                acc[0][nt] = __builtin_amdgcn_mfma_f32_16x16x32_bf16(afrag[0], b, acc[0][nt], 0,0,0);
                acc[1][nt] = __builtin_amdgcn_mfma_f32_16x16x32_bf16(afrag[1], b, acc[1][nt], 0,0,0);
            }
        }
        __syncthreads();    // A aliases sdist/sposf: drain K-loop before pass1
    }

    // ---------- parallel tree reduce + LN (shared by both halves) ----------
    // pass1: waves 0,1 write their partials to A / B
    if (w < 2) {
        float* R = (w == 0) ? Ar : Br;
        #pragma unroll
        for (int mt = 0; mt < 2; ++mt)
        #pragma unroll
        for (int nt = 0; nt < 8; ++nt)
        #pragma unroll
        for (int r = 0; r < 4; ++r)
            R[(mt*16 + quad*4 + r)*132 + nt*16 + l16] = acc[mt][nt][r];
    }
    __syncthreads();
    // pass2: waves 2,3 add into A / B
    if (w >= 2) {
        float* R = (w == 2) ? Ar : Br;
        #pragma unroll
        for (int mt = 0; mt < 2; ++mt)
        #pragma unroll
        for (int nt = 0; nt < 8; ++nt)
        #pragma unroll
        for (int r = 0; r < 4; ++r)
            R[(mt*16 + quad*4 + r)*132 + nt*16 + l16] += acc[mt][nt][r];
    }
    __syncthreads();
    // pass3: combine A+B in place (into A) fused with LN partial sums
    {
        int e = t >> 3, p = t & 7;
        float s = 0.f, s2 = 0.f;
        #pragma unroll
        for (int q = 0; q < 16; ++q) {
            int f = q*8 + p;                       // stride-8 sampling: <=2-way banks
            float x = Ar[e*132 + f] + Br[e*132 + f];
            Ar[e*132 + f] = x;
            s += x; s2 += x*x;
        }
        part[e*8+p] = s; part2[e*8+p] = s2;
    }
    __syncthreads();
    if (t < 32) {
        float s = 0.f, s2 = 0.f;
        #pragma unroll
        for (int p = 0; p < 8; ++p) { s += part[t*8+p]; s2 += part2[t*8+p]; }
        float mu = s * (1.0f/128.0f);
        float var = s2 * (1.0f/128.0f) - mu*mu;
        smu[t] = mu; srs[t] = rsqrtf(var + 1e-5f);
    }
    __syncthreads();
    for (int it = t; it < 32*32; it += 256) {
        int e = it >> 5, f = (it & 31)*4;
        float4 x = *(const float4*)&Ar[e*132 + f];
        float4 G = *(const float4*)&gW[f];
        float4 B = *(const float4*)&bW[f];
        float mu = smu[e], rs = srs[e];
        float4 r;
        r.x = G.x*(x.x - mu)*rs + B.x;
        r.y = G.y*(x.y - mu)*rs + B.y;
        r.z = G.z*(x.z - mu)*rs + B.z;
        r.w = G.w*(x.w - mu)*rs + B.w;
        *(float4*)&out[outBase + (size_t)(id0 + e)*128 + f] = r;
    }
}

extern "C" void kernel_launch(void* const* d_in, const int* in_sizes, int n_in,
                              void* d_out, int out_size, void* d_ws, size_t ws_size,
                              hipStream_t stream) {
    (void)in_sizes; (void)n_in; (void)out_size; (void)ws_size;
    const float* X     = (const float*)d_in[0];
    const float* mask  = (const float*)d_in[2];
    const float* amask = (const float*)d_in[3];
    const int*   ri    = (const int*)d_in[4];
    const int*   ch    = (const int*)d_in[6];
    const float* Wpos  = (const float*)d_in[7];
    const float* bpos  = (const float*)d_in[8];
    const float* We    = (const float*)d_in[9];
    const float* ge    = (const float*)d_in[10];
    const float* be    = (const float*)d_in[11];
    const float* Ws    = (const float*)d_in[12];
    const float* gs    = (const float*)d_in[13];
    const float* bs    = (const float*)d_in[14];

    float* out    = (float*)d_out;
    float* ws     = (float*)d_ws;
    float* coords = ws + WS_COORDS;
    float* Dnb    = ws + WS_DNB;
    int*   Eidx   = (int*)(ws + WS_EIDX);
    short* WpE    = (short*)(ws + WS_WPE);
    short* WpS    = (short*)(ws + WS_WPS);

    k_pre <<<dim3(900),  dim3(256), 0, stream>>>(X, mask, We, Ws, coords,
                                                 WpE, WpS, Dnb, Eidx, out);
    k_edge<<<dim3(3072), dim3(256), 0, stream>>>(coords, X, amask, WpE, WpS,
                                                 Dnb, Eidx, ri, ch, Wpos, bpos,
                                                 ge, be, gs, bs, out);
}